// Round 3
// baseline (43.642 us; speedup 1.0000x reference)
//
#include <hip/hip_runtime.h>

// LengthRegulator: B=32, T=256, D=512, DUR_MAX=12
// out[b, f, :] = xs[b, searchsorted(cumsum(ds[b]), f, 'right').clip(0,T-1), :]
//                if f < total[b] else 0.0
#define BB 32
#define TT 256
#define DD 512
#define DUR_MAX_ 12
#define MAX_FRAMES_ (TT * (DUR_MAX_ - 1))   // 2816
#define FRAMES_PER_BLOCK 32
#define D4 (DD / 4)                          // 128 float4 per frame
#define BLOCK_THREADS 256

typedef float f32x4 __attribute__((ext_vector_type(4)));

__global__ __launch_bounds__(BLOCK_THREADS)
void LengthRegulator_20332375179470_kernel(const float* __restrict__ xs,
                                           const int* __restrict__ ds,
                                           float* __restrict__ out)
{
    __shared__ int s_cs[TT];
    __shared__ int s_wsum[BLOCK_THREADS / 64];
    __shared__ int s_tok[FRAMES_PER_BLOCK];

    const int b    = blockIdx.y;
    const int f0   = blockIdx.x * FRAMES_PER_BLOCK;
    const int tid  = threadIdx.x;
    const int lane = tid & 63;
    const int wid  = tid >> 6;

    // ---- inclusive scan of ds row: shfl wave-scan + 1 barrier ----
    int v = ds[b * TT + tid];
    #pragma unroll
    for (int off = 1; off < 64; off <<= 1) {
        int n = __shfl_up(v, off, 64);
        if (lane >= off) v += n;
    }
    if (lane == 63) s_wsum[wid] = v;
    __syncthreads();
    int woff = 0;
    #pragma unroll
    for (int w = 0; w < BLOCK_THREADS / 64; ++w)
        if (w < wid) woff += s_wsum[w];
    s_cs[tid] = v + woff;
    __syncthreads();
    const int total = s_cs[TT - 1];

    // ---- token index per frame: first idx with cs[idx] > f ----
    if (tid < FRAMES_PER_BLOCK) {
        const int f = f0 + tid;
        if (f < total) {
            int lo = 0, hi = TT;
            while (lo < hi) {
                int mid = (lo + hi) >> 1;
                if (s_cs[mid] <= f) lo = mid + 1; else hi = mid;
            }
            if (lo > TT - 1) lo = TT - 1;
            s_tok[tid] = lo;
        } else {
            s_tok[tid] = -1;   // padded frame
        }
    }
    __syncthreads();

    // ---- copy 32 frames x 512 floats as float4, nontemporal stores ----
    const f32x4* xs4  = (const f32x4*)(xs + (size_t)b * TT * DD);
    f32x4*       out4 = (f32x4*)(out + ((size_t)b * MAX_FRAMES_ + f0) * DD);

    #pragma unroll
    for (int i = 0; i < (FRAMES_PER_BLOCK * D4) / BLOCK_THREADS; ++i) {
        const int l   = i * BLOCK_THREADS + tid;
        const int fl  = l >> 7;        // l / D4
        const int d4  = l & (D4 - 1);  // l % D4
        const int tok = s_tok[fl];
        f32x4 val = (f32x4)(0.f);
        if (tok >= 0) val = xs4[tok * D4 + d4];
        __builtin_nontemporal_store(val, &out4[l]);
    }
}

extern "C" void kernel_launch(void* const* d_in, const int* in_sizes, int n_in,
                              void* d_out, int out_size, void* d_ws, size_t ws_size,
                              hipStream_t stream) {
    const float* xs = (const float*)d_in[0];
    const int*   ds = (const int*)d_in[1];
    float*       out = (float*)d_out;

    dim3 grid(MAX_FRAMES_ / FRAMES_PER_BLOCK, BB);
    LengthRegulator_20332375179470_kernel<<<grid, BLOCK_THREADS, 0, stream>>>(xs, ds, out);
}

// Round 4
// 32.516 us; speedup vs baseline: 1.3422x; 1.3422x over previous
//
#include <hip/hip_runtime.h>

// LengthRegulator: B=32, T=256, D=512, DUR_MAX=12
// out[b, f, :] = xs[b, searchsorted(cumsum(ds[b]), f, 'right').clip(0,T-1), :]
//                if f < total[b] else 0.0
#define BB 32
#define TT 256
#define DD 512
#define DUR_MAX_ 12
#define MAX_FRAMES_ (TT * (DUR_MAX_ - 1))   // 2816
#define FRAMES_PER_BLOCK 64
#define D4 (DD / 4)                          // 128 float4 per frame
#define BLOCK_THREADS 256

typedef float f32x4 __attribute__((ext_vector_type(4)));

__global__ __launch_bounds__(BLOCK_THREADS)
void LengthRegulator_20332375179470_kernel(const float* __restrict__ xs,
                                           const int* __restrict__ ds,
                                           float* __restrict__ out)
{
    __shared__ int s_cs[TT];
    __shared__ int s_wsum[BLOCK_THREADS / 64];
    __shared__ int s_tok[FRAMES_PER_BLOCK];

    const int b    = blockIdx.y;
    const int f0   = blockIdx.x * FRAMES_PER_BLOCK;
    const int tid  = threadIdx.x;
    const int lane = tid & 63;
    const int wid  = tid >> 6;

    // ---- inclusive scan of ds row: shfl wave-scan + 1 barrier ----
    int v = ds[b * TT + tid];
    #pragma unroll
    for (int off = 1; off < 64; off <<= 1) {
        int n = __shfl_up(v, off, 64);
        if (lane >= off) v += n;
    }
    if (lane == 63) s_wsum[wid] = v;
    __syncthreads();
    int woff = 0;
    #pragma unroll
    for (int w = 0; w < BLOCK_THREADS / 64; ++w)
        if (w < wid) woff += s_wsum[w];
    s_cs[tid] = v + woff;
    __syncthreads();
    const int total = s_cs[TT - 1];

    // ---- token index per frame: first idx with cs[idx] > f ----
    if (tid < FRAMES_PER_BLOCK) {
        const int f = f0 + tid;
        if (f < total) {
            int lo = 0, hi = TT;
            while (lo < hi) {
                int mid = (lo + hi) >> 1;
                if (s_cs[mid] <= f) lo = mid + 1; else hi = mid;
            }
            if (lo > TT - 1) lo = TT - 1;
            s_tok[tid] = lo;
        } else {
            s_tok[tid] = -1;   // padded frame
        }
    }
    __syncthreads();

    // ---- copy 64 frames x 512 floats as float4, coalesced ----
    const f32x4* xs4  = (const f32x4*)(xs + (size_t)b * TT * DD);
    f32x4*       out4 = (f32x4*)(out + ((size_t)b * MAX_FRAMES_ + f0) * DD);

    #pragma unroll
    for (int i = 0; i < (FRAMES_PER_BLOCK * D4) / BLOCK_THREADS; ++i) {
        const int l   = i * BLOCK_THREADS + tid;
        const int fl  = l >> 7;        // l / D4
        const int d4  = l & (D4 - 1);  // l % D4
        const int tok = s_tok[fl];
        f32x4 val = (f32x4)(0.f);
        if (tok >= 0) val = xs4[tok * D4 + d4];
        out4[l] = val;
    }
}

extern "C" void kernel_launch(void* const* d_in, const int* in_sizes, int n_in,
                              void* d_out, int out_size, void* d_ws, size_t ws_size,
                              hipStream_t stream) {
    const float* xs = (const float*)d_in[0];
    const int*   ds = (const int*)d_in[1];
    float*       out = (float*)d_out;

    dim3 grid(MAX_FRAMES_ / FRAMES_PER_BLOCK, BB);
    LengthRegulator_20332375179470_kernel<<<grid, BLOCK_THREADS, 0, stream>>>(xs, ds, out);
}